// Round 12
// baseline (8175.919 us; speedup 1.0000x reference)
//
#include <hip/hip_runtime.h>
#include <math.h>

// VanillaRNN, bit-exact (R4-R11 PASS) + R12: 2 rows/thread + 2 barriers/step.
//
// Numerics (FROZEN — chaotic recurrence, bitwise match):
//   * per row i: z = single ascending-k FMA chain k=0..255, init 0, split in
//     program order: P (k 0..127) -> exact-float LDS handoff -> Q (k 128..255)
//     — identical op sequence (bit-safe since R7).
//   * z = ((W_hx*x_t) + chain) + bias_h, separately rounded, left-assoc
//   * tanh = Eigen/XLA fast-tanh WITH FMA (clamp 7.99881172180175781f)
//
// R12 theory (from R9 vs R11 A/B): step ~= LDS-broadcast occupancy + barrier
// drain (VALU hides under; the 2x "VALU inflation" is largely the gfx94x
// VALUBusy formula assuming 4 cyc/instr). R9: 512 reads + 2 barriers = 3570
// cyc; R11: 256 reads + 4 barriers = 5460 cyc => barrier ~600 cyc, read ~4
// cyc. This round: 256 reads AND 2 barriers.
//   * WG=256, 2 cols/WG, 256 WGs = 1 WG/CU, 1 wave/SIMD.
//   * P = tid 0..127: rows {r, r+128}, k in [0,128); Q = tid 128..255: rows
//     {r, r+128}, k in [128,256). Each b128 h-read feeds 8 FMAs (za, zv).
//   * 1 wave/SIMD budget = 512 VGPRs -> w[2][128] fully arch-resident.
//   * za/zv ILP-2 covers the 4-cyc FMA dep latency without a second wave.
//   * R9 2-barrier schedule kept verbatim.

#define TT 2048
#define BB 512
#define HH 256
#define CC 10
#define KH 128   // k-half per group

__device__ __forceinline__ float ref_tanhf(float x)
{
    const float a1  = 4.89352455891786e-03f;
    const float a3  = 6.37261928875436e-04f;
    const float a5  = 1.48572235717979e-05f;
    const float a7  = 5.12229709037114e-08f;
    const float a9  = -8.60467152213735e-11f;
    const float a11 = 2.00018790482477e-13f;
    const float a13 = -2.76076847742355e-16f;
    const float b0  = 4.89352518554385e-03f;
    const float b2  = 2.26843463243900e-03f;
    const float b4  = 1.18534705686654e-04f;
    const float b6  = 1.19825839466702e-06f;

    const float kClamp = 7.99881172180175781f;
    const float xc = fmaxf(fminf(x, kClamp), -kClamp);
    const float x2 = __fmul_rn(xc, xc);
    float p = fmaf(x2, a13, a11);
    p = fmaf(x2, p, a9);
    p = fmaf(x2, p, a7);
    p = fmaf(x2, p, a5);
    p = fmaf(x2, p, a3);
    p = fmaf(x2, p, a1);
    p = __fmul_rn(xc, p);
    float q = fmaf(x2, b6, b4);
    q = fmaf(x2, q, b2);
    q = fmaf(x2, q, b0);
    const float r = __fdiv_rn(p, q);
    return (fabsf(x) < 0.0004f) ? x : r;
}

__global__ __launch_bounds__(256, 1)
void rnn_fwd(const float* __restrict__ x,
             const float* __restrict__ W_hx,
             const float* __restrict__ W_hh,
             const float* __restrict__ W_ph,
             const float* __restrict__ bias_h,
             const float* __restrict__ bias_p,
             float* __restrict__ out)
{
    const int tid   = threadIdx.x;
    const int group = tid >> 7;          // 0 = P (k 0..127), 1 = Q (k 128..255)
    const int r     = tid & 127;         // rows r and r+128
    const int b0    = blockIdx.x * 2;    // two batch columns per WG

    __shared__ __align__(16) float xls[2][TT];        // 16 KB
    __shared__ __align__(16) float hbuf[2][2][HH];    // [col][parity][row] 4 KB
    __shared__ __align__(16) float zpart[2][HH];      // 2 KB

    // --- stage W_hh: rows r and r+128, k-half [128*group, +128) -> VGPRs ---
    float wa[KH], wb[KH];
    {
        const float* __restrict__ wra = W_hh + (size_t)r * HH + group * KH;
        const float* __restrict__ wrb = W_hh + (size_t)(r + 128) * HH + group * KH;
#pragma unroll
        for (int k = 0; k < KH; k += 4) {
            const float4 va = *reinterpret_cast<const float4*>(wra + k);
            wa[k] = va.x; wa[k + 1] = va.y; wa[k + 2] = va.z; wa[k + 3] = va.w;
            const float4 vb = *reinterpret_cast<const float4*>(wrb + k);
            wb[k] = vb.x; wb[k + 1] = vb.y; wb[k + 2] = vb.z; wb[k + 3] = vb.w;
        }
    }
#pragma unroll
    for (int k = 0; k < KH; ++k) {
        asm volatile("" : "+v"(wa[k]));
        asm volatile("" : "+v"(wb[k]));
    }

    // --- stage x rows (2*TT contiguous floats = 1024 float4) -> LDS ---
    {
        const float4* __restrict__ xsrc =
            reinterpret_cast<const float4*>(x + (size_t)b0 * TT);
        float4* __restrict__ xdst = reinterpret_cast<float4*>(&xls[0][0]);
#pragma unroll
        for (int j = 0; j < 4; ++j) {
            xdst[j * 256 + tid] = xsrc[j * 256 + tid];
        }
    }
    const float whxa = W_hx[r];
    const float whxb = W_hx[r + 128];
    const float bha  = bias_h[r];
    const float bhb  = bias_h[r + 128];

    // h(-1)=0 at parity 1 (step t reads (t&1)^1, writes t&1)
    hbuf[0][1][tid] = 0.0f;
    hbuf[1][1][tid] = 0.0f;
    __syncthreads();

#define CHAIN4(H4, K)                                                         \
    za = fmaf(wa[(K)],     H4.x, za);  zv = fmaf(wb[(K)],     H4.x, zv);      \
    za = fmaf(wa[(K) + 1], H4.y, za);  zv = fmaf(wb[(K) + 1], H4.y, zv);      \
    za = fmaf(wa[(K) + 2], H4.z, za);  zv = fmaf(wb[(K) + 2], H4.z, zv);      \
    za = fmaf(wa[(K) + 3], H4.w, za);  zv = fmaf(wb[(K) + 3], H4.w, zv);

// P half-chain: rows r, r+128; k = 0..127; init 0; exact partial to LDS.
#define PBODY(COL, T, RP)                                                     \
    {                                                                         \
        const float* __restrict__ h = &hbuf[(COL)][(RP)][0];                  \
        float za = 0.0f, zv = 0.0f;                                           \
        _Pragma("unroll")                                                     \
        for (int j = 0; j < KH; j += 4) {                                     \
            const float4 h4 = *reinterpret_cast<const float4*>(h + j);        \
            CHAIN4(h4, j)                                                     \
        }                                                                     \
        zpart[(COL)][r] = za;  zpart[(COL)][r + 128] = zv;                    \
    }

// Q half-chain: resume k = 128..255, then x/bias/tanh, write parity RP^1.
#define QBODY(COL, T, RP)                                                     \
    {                                                                         \
        const float* __restrict__ h = &hbuf[(COL)][(RP)][KH];                 \
        float za = zpart[(COL)][r], zv = zpart[(COL)][r + 128];               \
        _Pragma("unroll")                                                     \
        for (int j = 0; j < KH; j += 4) {                                     \
            const float4 h4 = *reinterpret_cast<const float4*>(h + j);        \
            CHAIN4(h4, j)                                                     \
        }                                                                     \
        const float xt = xls[(COL)][(T)];                                     \
        const float aa = __fmul_rn(whxa, xt);                                 \
        const float ab = __fmul_rn(whxb, xt);                                 \
        za = __fadd_rn(__fadd_rn(aa, za), bha);                               \
        zv = __fadd_rn(__fadd_rn(ab, zv), bhb);                               \
        hbuf[(COL)][(RP) ^ 1][r]       = ref_tanhf(za);                       \
        hbuf[(COL)][(RP) ^ 1][r + 128] = ref_tanhf(zv);                       \
    }

// One u-iteration with compile-time read-parity RP = (u&1)^1 (R9 schedule).
#define STEP(U, RP)                                                           \
    {                                                                         \
        if (group == 0) { PBODY(0, (U), (RP)) }                               \
        else if ((U) >= 1) { QBODY(1, (U) - 1, (RP) ^ 1) }                    \
        __syncthreads();                                                      \
        if (group == 0) { PBODY(1, (U), (RP)) }                               \
        else { QBODY(0, (U), (RP)) }                                          \
        __syncthreads();                                                      \
    }

    STEP(0, 1)
    for (int u = 1; u + 1 < TT; u += 2) {
        STEP(u, 0)
        STEP(u + 1, 1)
    }
    STEP(TT - 1, 0)                           // u = 2047 (odd -> rp = 0)
    if (group == 1) { QBODY(1, TT - 1, 0) }   // drain: col1, last step
    __syncthreads();

#undef STEP
#undef QBODY
#undef PBODY
#undef CHAIN4

    // epilogue: p[b,c] = sum_k h_T[k]*W_ph[c,k] + bias_p[c]
    // last step t = TT-1 wrote parity 1 for both columns.
    if (tid < 2 * CC) {
        const int col = tid / CC;
        const int c   = tid % CC;
        const float* __restrict__ wp = W_ph + (size_t)c * HH;
        const float* __restrict__ hf = hbuf[col][1];
        float pv = 0.0f;
#pragma unroll 8
        for (int k = 0; k < HH; ++k) {
            pv = fmaf(hf[k], wp[k], pv);
        }
        out[(size_t)(b0 + col) * CC + c] = __fadd_rn(pv, bias_p[c]);
    }
}

extern "C" void kernel_launch(void* const* d_in, const int* in_sizes, int n_in,
                              void* d_out, int out_size, void* d_ws, size_t ws_size,
                              hipStream_t stream) {
    const float* x      = (const float*)d_in[0];
    const float* W_hx   = (const float*)d_in[1];
    const float* W_hh   = (const float*)d_in[2];
    const float* W_ph   = (const float*)d_in[3];
    const float* bias_h = (const float*)d_in[4];
    const float* bias_p = (const float*)d_in[5];
    float* out = (float*)d_out;

    rnn_fwd<<<dim3(BB / 2), dim3(256), 0, stream>>>(x, W_hx, W_hh, W_ph, bias_h, bias_p, out);
}

// Round 14
// 3224.834 us; speedup vs baseline: 2.5353x; 2.5353x over previous
//
#include <hip/hip_runtime.h>
#include <math.h>

// VanillaRNN, bit-exact (R4-R12 PASS) + R14: barrier-free flag pipeline.
//
// Numerics (FROZEN — chaotic recurrence, bitwise match):
//   * per row i: z = single ascending-k FMA chain k=0..255, init 0, split in
//     program order: P (k 0..127) -> exact-float LDS handoff -> Q (k 128..255).
//   * z = ((W_hx*x_t) + chain) + bias_h, separately rounded, left-assoc
//   * tanh = Eigen/XLA fast-tanh WITH FMA (clamp 7.99881172180175781f)
//
// R14 theory: R13's compile fail proved VALU can't source AGPRs (v_fma a-src
// rejected) => 128 w/thread & 8 waves/CU is the forced shape (R9). R9's
// remaining cost: 2 x __syncthreads per step ~= 700 cyc each (from R9/R11
// regression algebra) = ~40% of the 3,570-cyc step, stalling all 8 waves at
// the slowest wave 4,096 times. Fix: producer/consumer flag sync:
//   P(col,u): spin  hdone[col] >= 4*u      (all Q done step u-1 for col)
//             compute k 0..127, write zpart[col][u&1], arrive zdone[col]++
//   Q(col,u): spin  zdone[col] >= 4*(u+1)  (all P done step u for col)
//             resume chain, tanh, write hbuf[col][u&1], arrive hdone[col]++
// WAR safety: zpart parity-buffered; h WAR covered transitively (P(col,u)
// waits all Q(col,u-1); in-wave program order does the rest). All 8 waves
// of the single 512-thread WG are co-resident => spin cannot deadlock.
// Waves slip independently (Q col0 overlaps P col1) — no global drain.

#define TT 2048
#define BB 512
#define HH 256
#define CC 10
#define KH 128   // k-half per group

__device__ __forceinline__ float ref_tanhf(float x)
{
    const float a1  = 4.89352455891786e-03f;
    const float a3  = 6.37261928875436e-04f;
    const float a5  = 1.48572235717979e-05f;
    const float a7  = 5.12229709037114e-08f;
    const float a9  = -8.60467152213735e-11f;
    const float a11 = 2.00018790482477e-13f;
    const float a13 = -2.76076847742355e-16f;
    const float b0  = 4.89352518554385e-03f;
    const float b2  = 2.26843463243900e-03f;
    const float b4  = 1.18534705686654e-04f;
    const float b6  = 1.19825839466702e-06f;

    const float kClamp = 7.99881172180175781f;
    const float xc = fmaxf(fminf(x, kClamp), -kClamp);
    const float x2 = __fmul_rn(xc, xc);
    float p = fmaf(x2, a13, a11);
    p = fmaf(x2, p, a9);
    p = fmaf(x2, p, a7);
    p = fmaf(x2, p, a5);
    p = fmaf(x2, p, a3);
    p = fmaf(x2, p, a1);
    p = __fmul_rn(xc, p);
    float q = fmaf(x2, b6, b4);
    q = fmaf(x2, q, b2);
    q = fmaf(x2, q, b0);
    const float r = __fdiv_rn(p, q);
    return (fabsf(x) < 0.0004f) ? x : r;
}

__global__ __launch_bounds__(512, 2)
void rnn_fwd(const float* __restrict__ x,
             const float* __restrict__ W_hx,
             const float* __restrict__ W_hh,
             const float* __restrict__ W_ph,
             const float* __restrict__ bias_h,
             const float* __restrict__ bias_p,
             float* __restrict__ out)
{
    const int tid   = threadIdx.x;
    const int group = tid >> 8;        // 0 = P (k 0..127), 1 = Q (k 128..255)
    const int i     = tid & (HH - 1);  // hidden row
    const int lane  = tid & 63;
    const int b0    = blockIdx.x * 2;  // two batch columns per WG

    __shared__ __align__(16) float xls[2][TT];         // 16 KB
    __shared__ __align__(16) float hbuf[2][2][HH];     // [col][parity][row]
    __shared__ __align__(16) float zpart[2][2][HH];    // [col][parity][row]
    __shared__ int zdone[2];                           // P arrivals per col
    __shared__ int hdone[2];                           // Q arrivals per col

    // --- stage: this thread's half-row of W_hh -> 128 VGPRs ---
    float w[KH];
    const float* __restrict__ wrow = W_hh + (size_t)i * HH + group * KH;
#pragma unroll
    for (int k = 0; k < KH; k += 4) {
        const float4 v = *reinterpret_cast<const float4*>(wrow + k);
        w[k] = v.x; w[k + 1] = v.y; w[k + 2] = v.z; w[k + 3] = v.w;
    }
#pragma unroll
    for (int k = 0; k < KH; ++k) {
        asm volatile("" : "+v"(w[k]));   // block rematerialization
    }

    // --- stage x rows (2*TT contiguous floats) -> LDS ---
    {
        const float4* __restrict__ xsrc =
            reinterpret_cast<const float4*>(x + (size_t)b0 * TT);
        float4* __restrict__ xdst = reinterpret_cast<float4*>(&xls[0][0]);
        xdst[tid]       = xsrc[tid];
        xdst[512 + tid] = xsrc[512 + tid];
    }
    const float whx = W_hx[i];     // used by Q only
    const float bh  = bias_h[i];   // used by Q only

    // h(-1)=0 at parity 1 (step u reads (u&1)^1, writes u&1); flags zero.
    hbuf[group][1][i] = 0.0f;
    if (tid == 0) { zdone[0] = 0; zdone[1] = 0; hdone[0] = 0; hdone[1] = 0; }
    __syncthreads();   // one-time init barrier only

// release-arrive: drain own LDS writes, then one add per wave
#define ARRIVE(FLAG)                                                          \
    {                                                                         \
        __threadfence_block();                                                \
        if (lane == 0) atomicAdd(&(FLAG), 1);                                 \
    }
// acquire-spin: all 64 lanes poll same address (broadcast), uniform exit
#define SPIN(FLAG, TGT)                                                       \
    {                                                                         \
        volatile int* f_ = &(FLAG);                                           \
        while (*f_ < (TGT)) {}                                                \
        __threadfence_block();                                                \
    }

// P body: wait h(u-1), chain k=0..127 from 0, publish zpart, arrive.
#define PSTEP(COL, U, RP)                                                     \
    {                                                                         \
        SPIN(hdone[(COL)], 4 * (U))                                           \
        const float* __restrict__ h = &hbuf[(COL)][(RP)][0];                  \
        float z = 0.0f;                                                       \
        _Pragma("unroll")                                                     \
        for (int k = 0; k < KH; k += 4) {                                     \
            const float4 h4 = *reinterpret_cast<const float4*>(h + k);        \
            z = fmaf(w[k],     h4.x, z);                                      \
            z = fmaf(w[k + 1], h4.y, z);                                      \
            z = fmaf(w[k + 2], h4.z, z);                                      \
            z = fmaf(w[k + 3], h4.w, z);                                      \
        }                                                                     \
        zpart[(COL)][(RP) ^ 1][i] = z;                                        \
        ARRIVE(zdone[(COL)])                                                  \
    }

// Q body: wait zpart(u), resume chain k=128..255, x/bias/tanh, publish h.
#define QSTEP(COL, U, RP)                                                     \
    {                                                                         \
        SPIN(zdone[(COL)], 4 * ((U) + 1))                                     \
        const float* __restrict__ h = &hbuf[(COL)][(RP)][KH];                 \
        float z = zpart[(COL)][(RP) ^ 1][i];                                  \
        _Pragma("unroll")                                                     \
        for (int k = 0; k < KH; k += 4) {                                     \
            const float4 h4 = *reinterpret_cast<const float4*>(h + k);        \
            z = fmaf(w[k],     h4.x, z);                                      \
            z = fmaf(w[k + 1], h4.y, z);                                      \
            z = fmaf(w[k + 2], h4.z, z);                                      \
            z = fmaf(w[k + 3], h4.w, z);                                      \
        }                                                                     \
        const float a0 = __fmul_rn(whx, xls[(COL)][(U)]);                     \
        z = __fadd_rn(__fadd_rn(a0, z), bh);                                  \
        hbuf[(COL)][(RP) ^ 1][i] = ref_tanhf(z);                              \
        ARRIVE(hdone[(COL)])                                                  \
    }

    if (group == 0) {
        for (int u = 0; u < TT; u += 2) {
            PSTEP(0, u, 1)     PSTEP(1, u, 1)        // even u: read parity 1
            PSTEP(0, u + 1, 0) PSTEP(1, u + 1, 0)    // odd  u: read parity 0
        }
    } else {
        for (int u = 0; u < TT; u += 2) {
            QSTEP(0, u, 1)     QSTEP(1, u, 1)
            QSTEP(0, u + 1, 0) QSTEP(1, u + 1, 0)
        }
    }
    __syncthreads();   // final drain before epilogue

#undef QSTEP
#undef PSTEP
#undef SPIN
#undef ARRIVE

    // epilogue: p[b,c] = sum_k h_T[k]*W_ph[c,k] + bias_p[c]
    // last step u = TT-1 wrote parity (TT-1)&1 = 1.
    if (tid < 2 * CC) {
        const int col = tid / CC;
        const int c   = tid % CC;
        const float* __restrict__ wp = W_ph + (size_t)c * HH;
        const float* __restrict__ hf = hbuf[col][1];
        float pv = 0.0f;
#pragma unroll 8
        for (int k = 0; k < HH; ++k) {
            pv = fmaf(hf[k], wp[k], pv);
        }
        out[(size_t)(b0 + col) * CC + c] = __fadd_rn(pv, bias_p[c]);
    }
}

extern "C" void kernel_launch(void* const* d_in, const int* in_sizes, int n_in,
                              void* d_out, int out_size, void* d_ws, size_t ws_size,
                              hipStream_t stream) {
    const float* x      = (const float*)d_in[0];
    const float* W_hx   = (const float*)d_in[1];
    const float* W_hh   = (const float*)d_in[2];
    const float* W_ph   = (const float*)d_in[3];
    const float* bias_h = (const float*)d_in[4];
    const float* bias_p = (const float*)d_in[5];
    float* out = (float*)d_out;

    rnn_fwd<<<dim3(BB / 2), dim3(512), 0, stream>>>(x, W_hx, W_hh, W_ph, bias_h, bias_p, out);
}